// Round 4
// baseline (436.931 us; speedup 1.0000x reference)
//
#include <hip/hip_runtime.h>

typedef _Float16 f16;
typedef __attribute__((ext_vector_type(8))) _Float16 f16x8;
typedef __attribute__((ext_vector_type(4))) _Float16 f16x4;
typedef __attribute__((ext_vector_type(4))) float    f32x4;

#define MFMA_F16(a,b,c) __builtin_amdgcn_mfma_f32_16x16x32_f16((a),(b),(c),0,0,0)

// problem constants
constexpr int Bc   = 4;
constexpr int Sc   = 2048;
constexpr int Hc   = 12;
constexpr int Dc   = 100;
constexpr int HIDc = 1200;
constexpr int BH   = Bc * Hc;    // 48
constexpr int DP   = 128;        // padded head dim (dim 100 carries the bias trick)
constexpr int LDK  = 1216;       // padded inner dim for x16/w16 (19 * 64)
constexpr int NWP  = 1280;       // padded row count for w16 (N-tile overrun)
constexpr int KVT  = 64;         // kv tile length
constexpr int NT   = Sc / KVT;   // 32 tiles per (b,h)
constexpr int TE   = KVT * DP;   // 8192 elems per K or V tile (16 KB)

// async global->LDS, 16B per lane (linear dest = base + lane*16)
typedef const __attribute__((address_space(1))) void GV;
typedef __attribute__((address_space(3))) void LV;
__device__ __forceinline__ void gload16(const f16* g, f16* l) {
    __builtin_amdgcn_global_load_lds((GV*)g, (LV*)l, 16, 0, 0);
}

// ---------------- fp32 -> fp16 convert with zero padding (x4 vectorized) ----
__global__ void cvt_pad4_kernel(const float* __restrict__ src, f16* __restrict__ dst,
                                int srcR, int srcC, int dstC, int total4) {
    int i = blockIdx.x * 256 + threadIdx.x;
    if (i >= total4) return;
    int idx = i * 4;
    int r = idx / dstC, c = idx - r * dstC;     // dstC % 4 == 0 -> no row straddle
    f16x4 o;
    if (r < srcR && c + 3 < srcC) {
        float4 v = *(const float4*)(src + r * srcC + c);
        o[0] = (f16)v.x; o[1] = (f16)v.y; o[2] = (f16)v.z; o[3] = (f16)v.w;
    } else {
#pragma unroll
        for (int e = 0; e < 4; ++e) {
            float vv = (r < srcR && c + e < srcC) ? src[r * srcC + c + e] : 0.f;
            o[e] = (f16)vv;
        }
    }
    *(f16x4*)(dst + idx) = o;
}

// pads: Q linear d=[100,128) (1 at d=100, 0 else); K tiled-swizzled d=[100,128)
// (bias at d=100, 0 else); V tiled-swizzled rows d=[100,128) zero.
// bias: Q[s,100]=1 (scaled by 10*log2e/(L+1) in attn), K[t,100]=alibi/10+mask*(L+1)/10
__global__ void pad_bufs_kernel(f16* __restrict__ q, f16* __restrict__ kT, f16* __restrict__ vT,
                                const float* __restrict__ alibi, const float* __restrict__ amask,
                                const int* __restrict__ lidx) {
    int i = blockIdx.x * 256 + threadIdx.x;
    constexpr int PADW = DP - Dc;              // 28
    if (i >= BH * Sc * PADW) return;
    int dd = i % PADW;
    int rs = i / PADW;                          // bh*S + t
    int d  = Dc + dd;
    int bh = rs >> 11, t = rs & (Sc - 1);
    int b  = bh / Hc;
    q[rs * DP + d] = (d == Dc) ? (f16)1.0f : (f16)0.f;
    const size_t tb = ((size_t)bh * NT + (t >> 6)) * TE;
    f16 kv = (f16)0.f;
    if (d == Dc) {
        float bias = alibi[rs] * 0.1f + amask[b * Sc + t] * ((float)(lidx[0] + 1) * 0.1f);
        kv = (f16)bias;
    }
    kT[tb + (t & 63) * DP + (d ^ ((t & 7) << 3))] = kv;
    vT[tb + d * 64 + ((t & 63) ^ ((d & 7) << 3))] = (f16)0.f;
}

// ---------------- B^T GEMM: C[m,n] = sum_k A[m,k]*B[n,k], f16 in / f32 acc --
// K-loop fixed at 19 x 64 = 1216 (inputs zero-padded; mode 3 relies on zero
// B-columns to neutralize the 16-element row overrun of lda=1200 A reads).
// mode 0: Q -> (b,h,s,d) padded-128 linear
// mode 1: K -> [bh][tile][t&63][d ^ ((t&7)<<3)] swizzled 16KB tiles
// mode 2: V -> [bh][tile][d][(t&63) ^ ((d&7)<<3)] swizzled 16KB tiles
// mode 3: f32 row-major M x 1200 (final out)
__launch_bounds__(256)
__global__ void gemm_bt_kernel(const f16* __restrict__ A, int lda,
                               const f16* __restrict__ Bm,
                               f16* __restrict__ o16,
                               float* __restrict__ oF,
                               int mode) {
    __shared__ f16 As[128][64];
    __shared__ f16 Bs[128][64];

    const int tid  = threadIdx.x;
    const int lane = tid & 63, wave = tid >> 6;
    const int wm = wave >> 1, wn = wave & 1;     // 2x2 wave grid, 64x64 per wave
    const int n15 = lane & 15, g = lane >> 4;
    const int brow = blockIdx.x * 128;
    const int bcol = blockIdx.y * 128;

    f32x4 acc[4][4];
#pragma unroll
    for (int i = 0; i < 4; ++i)
#pragma unroll
        for (int j = 0; j < 4; ++j)
            acc[i][j] = (f32x4){0.f, 0.f, 0.f, 0.f};

    const f16* Ab = A  + (size_t)brow * lda;
    const f16* Bb = Bm + (size_t)bcol * LDK;

    for (int kt = 0; kt < LDK / 64; ++kt) {      // 19
        const int k0 = kt << 6;
        __syncthreads();                         // all waves done reading prev tile
#pragma unroll
        for (int j = 0; j < 4; ++j) {
            const int c   = j * 256 + tid;       // 1024 chunks of 16B
            const int row = c >> 3;
            const int co  = (c & 7) * 8;
            gload16(Ab + (size_t)row * lda + k0 + co, &As[0][0] + c * 8);
            gload16(Bb + (size_t)row * LDK + k0 + co, &Bs[0][0] + c * 8);
        }
        __syncthreads();                         // drains vmcnt(0) before barrier
#pragma unroll
        for (int kc = 0; kc < 2; ++kc) {
            f16x8 af[4], bf[4];
#pragma unroll
            for (int i = 0; i < 4; ++i)
                af[i] = *(const f16x8*)&As[wm * 64 + i * 16 + n15][kc * 32 + g * 8];
#pragma unroll
            for (int i = 0; i < 4; ++i)
                bf[i] = *(const f16x8*)&Bs[wn * 64 + i * 16 + n15][kc * 32 + g * 8];
#pragma unroll
            for (int mi = 0; mi < 4; ++mi)
#pragma unroll
                for (int ni = 0; ni < 4; ++ni)
                    acc[mi][ni] = MFMA_F16(af[mi], bf[ni], acc[mi][ni]);
        }
    }

    // epilogue — C/D frag: row = 4*g + r, col = n15
#pragma unroll
    for (int mi = 0; mi < 4; ++mi) {
        const int m0 = brow + wm * 64 + mi * 16 + g * 4;   // 4-aligned
        const int b  = m0 >> 11;
        const int s0 = m0 & (Sc - 1);
#pragma unroll
        for (int ni = 0; ni < 4; ++ni) {
            const int n = bcol + wn * 64 + ni * 16 + n15;
            if (n >= HIDc) continue;
            if (mode == 0) {
                const int h = n / 100, d = n - h * 100;
                f16* dst = o16 + ((size_t)(b * Hc + h) * Sc + s0) * DP + d;
#pragma unroll
                for (int r = 0; r < 4; ++r)
                    dst[r * DP] = (f16)acc[mi][ni][r];
            } else if (mode == 1) {
                const int h = n / 100, d = n - h * 100;
                const size_t tb = ((size_t)(b * Hc + h) * NT + (s0 >> 6)) * TE;
#pragma unroll
                for (int r = 0; r < 4; ++r) {
                    const int t = s0 + r;                  // same tile for r=0..3
                    o16[tb + (t & 63) * DP + (d ^ ((t & 7) << 3))] = (f16)acc[mi][ni][r];
                }
            } else if (mode == 2) {
                const int h = n / 100, d = n - h * 100;
                const size_t tb = ((size_t)(b * Hc + h) * NT + (s0 >> 6)) * TE;
                f16x4 pk;
#pragma unroll
                for (int r = 0; r < 4; ++r) pk[r] = (f16)acc[mi][ni][r];
                *(f16x4*)(o16 + tb + d * 64 + ((s0 & 63) ^ ((d & 7) << 3))) = pk;
            } else {
                float* dst = oF + (size_t)m0 * HIDc + n;
#pragma unroll
                for (int r = 0; r < 4; ++r)
                    dst[r * HIDc] = acc[mi][ni][r];
            }
        }
    }
}

// ---------------- fused flash attention (swapped-operand, log2 domain) -------
// grid (16, 48). 4 waves/block, 32 q-rows each. K/V staged via global_load_lds
// from pre-swizzled contiguous tiles; all LDS reads share sx=(n15&7)<<3 XOR.
__launch_bounds__(256)
__global__ void attn_kernel(const f16* __restrict__ Qp, const f16* __restrict__ KpT,
                            const f16* __restrict__ VpT, const int* __restrict__ lidx,
                            f16* __restrict__ outp) {
    __shared__ f16 Kl[64][128];        // 16 KB, swizzled
    __shared__ f16 Vl[128][64];        // 16 KB, swizzled
    __shared__ f16 Pl[4][32][64];      // 16 KB, per-wave, swizzled

    const int tid  = threadIdx.x;
    const int lane = tid & 63, wave = tid >> 6;
    const int n15 = lane & 15, g = lane >> 4;
    const int sx  = (n15 & 7) << 3;    // shared XOR swizzle term (row&7 == n15&7 at all read sites)
    const int bh = blockIdx.y;
    const int qr0 = blockIdx.x * 128 + wave * 32;

    // log2-domain scale: exp(s*10/(L+1)) == exp2(s*10*log2e/(L+1))
    const float scale = 10.f * 1.44269504f / (float)(lidx[0] + 1);

    // hoist Q (32 rows x 128 d) into registers, pre-scaled
    const f16* Qb = Qp + ((size_t)bh * Sc + qr0) * DP;
    f16x8 qreg[2][4];
#pragma unroll
    for (int qf = 0; qf < 2; ++qf)
#pragma unroll
        for (int kc = 0; kc < 4; ++kc) {
            f16x8 v = *(const f16x8*)(Qb + (qf * 16 + n15) * DP + kc * 32 + g * 8);
#pragma unroll
            for (int e = 0; e < 8; ++e)
                v[e] = (f16)((float)v[e] * scale);
            qreg[qf][kc] = v;
        }

    float m_run[2] = {-1e30f, -1e30f};
    float l_run[2] = {0.f, 0.f};
    f32x4 accO[2][7];                  // O^T: d = df*16 + g*4 + r, q = n15
#pragma unroll
    for (int qf = 0; qf < 2; ++qf)
#pragma unroll
        for (int df = 0; df < 7; ++df)
            accO[qf][df] = (f32x4){0.f, 0.f, 0.f, 0.f};

    const f16* Ksrc = KpT + (size_t)bh * NT * TE;
    const f16* Vsrc = VpT + (size_t)bh * NT * TE;
    f16* KlB = &Kl[0][0];
    f16* VlB = &Vl[0][0];

    for (int tile = 0; tile < NT; ++tile) {
        __syncthreads();               // everyone done reading prev tile LDS
#pragma unroll
        for (int j = 0; j < 4; ++j) {
            const int c8 = (j * 256 + tid) * 8;
            gload16(Ksrc + c8, KlB + c8);
            gload16(Vsrc + c8, VlB + c8);
        }
        Ksrc += TE; Vsrc += TE;
        __syncthreads();               // implicit vmcnt(0) drain

        // S^T = K Q^T per wave: sc[qf][tf], lane holds q=n15, t=tf*16+g*4+r
        f32x4 sc[2][4];
#pragma unroll
        for (int qf = 0; qf < 2; ++qf)
#pragma unroll
            for (int tf = 0; tf < 4; ++tf)
                sc[qf][tf] = (f32x4){0.f, 0.f, 0.f, 0.f};
#pragma unroll
        for (int kc = 0; kc < 4; ++kc) {
            f16x8 kf[4];
#pragma unroll
            for (int tf = 0; tf < 4; ++tf)
                kf[tf] = *(const f16x8*)&Kl[tf * 16 + n15][(kc * 32 + g * 8) ^ sx];
#pragma unroll
            for (int qf = 0; qf < 2; ++qf)
#pragma unroll
                for (int tf = 0; tf < 4; ++tf)
                    sc[qf][tf] = MFMA_F16(kf[tf], qreg[qf][kc], sc[qf][tf]);
        }

        // tile max per q (lane-local 16 vals + 2 shfl)
        float tmax[2];
#pragma unroll
        for (int qf = 0; qf < 2; ++qf) {
            float m0 = fmaxf(fmaxf(sc[qf][0][0], sc[qf][0][1]), fmaxf(sc[qf][0][2], sc[qf][0][3]));
#pragma unroll
            for (int tf = 1; tf < 4; ++tf)
                m0 = fmaxf(m0, fmaxf(fmaxf(sc[qf][tf][0], sc[qf][tf][1]),
                                     fmaxf(sc[qf][tf][2], sc[qf][tf][3])));
            m0 = fmaxf(m0, __shfl_xor(m0, 16));
            m0 = fmaxf(m0, __shfl_xor(m0, 32));
            tmax[qf] = m0;
        }

        // defer-max (T13): rescale only when a q exceeds its running max by >8
        if (__any((tmax[0] > m_run[0] + 8.f) || (tmax[1] > m_run[1] + 8.f))) {
#pragma unroll
            for (int qf = 0; qf < 2; ++qf) {
                const float mn = fmaxf(m_run[qf], tmax[qf]);
                const float al = exp2f(m_run[qf] - mn);
                m_run[qf] = mn;
                l_run[qf] *= al;
#pragma unroll
                for (int df = 0; df < 7; ++df) {
                    accO[qf][df][0] *= al; accO[qf][df][1] *= al;
                    accO[qf][df][2] *= al; accO[qf][df][3] *= al;
                }
            }
        }

        // P = exp2(s - m), row-sum, pack to LDS (swizzled b64 per (qf,tf))
#pragma unroll
        for (int qf = 0; qf < 2; ++qf) {
            float ps = 0.f;
#pragma unroll
            for (int tf = 0; tf < 4; ++tf) {
                f16x4 pk;
#pragma unroll
                for (int r = 0; r < 4; ++r) {
                    const float p = exp2f(sc[qf][tf][r] - m_run[qf]);
                    ps += p;
                    pk[r] = (f16)p;
                }
                *(f16x4*)&Pl[wave][qf * 16 + n15][(tf * 16 + g * 4) ^ sx] = pk;
            }
            ps += __shfl_xor(ps, 16);
            ps += __shfl_xor(ps, 32);
            l_run[qf] += ps;
        }

        // O^T += V^T P^T (no barrier: Pl is per-wave)
        // B-frag for output block qf needs P rows qf*16 + n15 (q = column of O^T).
#pragma unroll
        for (int kc = 0; kc < 2; ++kc) {
            f16x8 pa[2];
#pragma unroll
            for (int qf = 0; qf < 2; ++qf)
                pa[qf] = *(const f16x8*)&Pl[wave][qf * 16 + n15][(kc * 32 + g * 8) ^ sx];
#pragma unroll
            for (int df = 0; df < 7; ++df) {
                const f16x8 vb = *(const f16x8*)&Vl[df * 16 + n15][(kc * 32 + g * 8) ^ sx];
#pragma unroll
                for (int qf = 0; qf < 2; ++qf)
                    accO[qf][df] = MFMA_F16(vb, pa[qf], accO[qf][df]);
            }
        }
    }

    // epilogue: lane holds O[q=n15][d=df*16+g*4+r] -> packed f16x4 stores
#pragma unroll
    for (int qf = 0; qf < 2; ++qf) {
        const float rl = 1.f / l_run[qf];
        const int qrow = qr0 + qf * 16 + n15;
#pragma unroll
        for (int df = 0; df < 7; ++df) {
            const int d0 = df * 16 + g * 4;
            if (d0 < Dc) {
                f16x4 o;
#pragma unroll
                for (int r = 0; r < 4; ++r)
                    o[r] = (f16)(accO[qf][df][r] * rl);
                *(f16x4*)(outp + ((size_t)bh * Sc + qrow) * Dc + d0) = o;
            }
        }
    }
}

// ---------------- launcher ----------------
extern "C" void kernel_launch(void* const* d_in, const int* in_sizes, int n_in,
                              void* d_out, int out_size, void* d_ws, size_t ws_size,
                              hipStream_t stream) {
    const float* x     = (const float*)d_in[0];
    const float* alibi = (const float*)d_in[1];
    const float* amask = (const float*)d_in[2];
    const float* wq    = (const float*)d_in[3];
    const float* wk    = (const float*)d_in[4];
    const float* wv    = (const float*)d_in[5];
    const float* wo    = (const float*)d_in[6];
    const int*   lidx  = (const int*)d_in[7];
    float* out = (float*)d_out;

    char* p = (char*)d_ws;
    auto carve = [&](size_t bytes) {
        char* q = p;
        p += (bytes + 255) & ~size_t(255);
        return q;
    };
    f16* x16  = (f16*)carve((size_t)(Bc * Sc) * LDK * 2);        // 8192 x 1216
    f16* wq16 = (f16*)carve((size_t)NWP * LDK * 2);              // 1280 x 1216
    f16* wk16 = (f16*)carve((size_t)NWP * LDK * 2);
    f16* wv16 = (f16*)carve((size_t)NWP * LDK * 2);
    f16* wo16 = (f16*)carve((size_t)NWP * LDK * 2);
    f16* QpL  = (f16*)carve((size_t)BH * Sc * DP * 2);           // (bh,s,128) linear
    f16* KpT  = (f16*)carve((size_t)BH * NT * TE * 2);           // swizzled tiles
    f16* VpT  = (f16*)carve((size_t)BH * NT * TE * 2);           // swizzled tiles
    f16* comb = (f16*)carve((size_t)BH * Sc * Dc * 2 + 4096);    // + overrun slack

    // 1) fp16 conversions (+ zero pads), x4-vectorized
    {
        int total4 = Bc * Sc * LDK / 4;
        cvt_pad4_kernel<<<(total4 + 255) / 256, 256, 0, stream>>>(x, x16, Bc * Sc, HIDc, LDK, total4);
    }
    {
        int total4 = NWP * LDK / 4;
        int nb = (total4 + 255) / 256;
        cvt_pad4_kernel<<<nb, 256, 0, stream>>>(wq, wq16, HIDc, HIDc, LDK, total4);
        cvt_pad4_kernel<<<nb, 256, 0, stream>>>(wk, wk16, HIDc, HIDc, LDK, total4);
        cvt_pad4_kernel<<<nb, 256, 0, stream>>>(wv, wv16, HIDc, HIDc, LDK, total4);
        cvt_pad4_kernel<<<nb, 256, 0, stream>>>(wo, wo16, HIDc, HIDc, LDK, total4);
    }
    // 2) pads of Q/K/V; K d=100 carries the alibi+mask bias (log2-domain trick)
    {
        int total = BH * Sc * (DP - Dc);
        pad_bufs_kernel<<<(total + 255) / 256, 256, 0, stream>>>(QpL, KpT, VpT, alibi, amask, lidx);
    }
    // 3) projections
    dim3 gg(64, 10);
    gemm_bt_kernel<<<gg, 256, 0, stream>>>(x16, LDK, wq16, QpL, nullptr, 0);
    gemm_bt_kernel<<<gg, 256, 0, stream>>>(x16, LDK, wk16, KpT, nullptr, 1);
    gemm_bt_kernel<<<gg, 256, 0, stream>>>(x16, LDK, wv16, VpT, nullptr, 2);
    // 4) fused attention
    attn_kernel<<<dim3(Sc / 128, BH), 256, 0, stream>>>(QpL, KpT, VpT, lidx, comb);
    // 5) output projection (reads comb linearly as 8192 x 1200; 16-elem row
    //    overrun lands on wo16's zero K-columns)
    gemm_bt_kernel<<<gg, 256, 0, stream>>>(comb, HIDc, wo16, nullptr, out, 3);
}

// Round 5
// 407.610 us; speedup vs baseline: 1.0719x; 1.0719x over previous
//
#include <hip/hip_runtime.h>

typedef _Float16 f16;
typedef __attribute__((ext_vector_type(8))) _Float16 f16x8;
typedef __attribute__((ext_vector_type(4))) _Float16 f16x4;
typedef __attribute__((ext_vector_type(4))) float    f32x4;

#define MFMA_F16(a,b,c) __builtin_amdgcn_mfma_f32_16x16x32_f16((a),(b),(c),0,0,0)

// problem constants
constexpr int Bc   = 4;
constexpr int Sc   = 2048;
constexpr int Hc   = 12;
constexpr int Dc   = 100;
constexpr int HIDc = 1200;
constexpr int BH   = Bc * Hc;    // 48
constexpr int DP   = 128;        // padded head dim (dim 100 carries the bias trick)
constexpr int LDK  = 1216;       // padded inner dim for x16/w16 (19 * 64)
constexpr int NWP  = 1280;       // padded row count for w16 (N-tile overrun)
constexpr int KVT  = 64;         // kv tile length
constexpr int NT   = Sc / KVT;   // 32 tiles per (b,h)
constexpr int TE   = KVT * DP;   // 8192 elems per K or V tile (16 KB)

// async global->LDS, 16B per lane (linear dest = base + lane*16)
typedef const __attribute__((address_space(1))) void GV;
typedef __attribute__((address_space(3))) void LV;
__device__ __forceinline__ void gload16(const f16* g, f16* l) {
    __builtin_amdgcn_global_load_lds((GV*)g, (LV*)l, 16, 0, 0);
}

// ---------------- fp32 -> fp16 convert with zero padding (x4 vectorized) ----
__global__ void cvt_pad4_kernel(const float* __restrict__ src, f16* __restrict__ dst,
                                int srcR, int srcC, int dstC, int total4) {
    int i = blockIdx.x * 256 + threadIdx.x;
    if (i >= total4) return;
    int idx = i * 4;
    int r = idx / dstC, c = idx - r * dstC;     // dstC % 4 == 0 -> no row straddle
    f16x4 o;
    if (r < srcR && c + 3 < srcC) {
        float4 v = *(const float4*)(src + r * srcC + c);
        o[0] = (f16)v.x; o[1] = (f16)v.y; o[2] = (f16)v.z; o[3] = (f16)v.w;
    } else {
#pragma unroll
        for (int e = 0; e < 4; ++e) {
            float vv = (r < srcR && c + e < srcC) ? src[r * srcC + c + e] : 0.f;
            o[e] = (f16)vv;
        }
    }
    *(f16x4*)(dst + idx) = o;
}

// pads: Q linear d=[100,128) (1 at d=100, 0 else); K tiled-swizzled d=[100,128)
// (bias at d=100, 0 else); V tiled-swizzled rows d=[100,128) zero.
// bias: Q[s,100]=1 (scaled by 10*log2e/(L+1) in attn), K[t,100]=alibi/10+mask*(L+1)/10
__global__ void pad_bufs_kernel(f16* __restrict__ q, f16* __restrict__ kT, f16* __restrict__ vT,
                                const float* __restrict__ alibi, const float* __restrict__ amask,
                                const int* __restrict__ lidx) {
    int i = blockIdx.x * 256 + threadIdx.x;
    constexpr int PADW = DP - Dc;              // 28
    if (i >= BH * Sc * PADW) return;
    int dd = i % PADW;
    int rs = i / PADW;                          // bh*S + t
    int d  = Dc + dd;
    int bh = rs >> 11, t = rs & (Sc - 1);
    int b  = bh / Hc;
    q[rs * DP + d] = (d == Dc) ? (f16)1.0f : (f16)0.f;
    const size_t tb = ((size_t)bh * NT + (t >> 6)) * TE;
    f16 kv = (f16)0.f;
    if (d == Dc) {
        float bias = alibi[rs] * 0.1f + amask[b * Sc + t] * ((float)(lidx[0] + 1) * 0.1f);
        kv = (f16)bias;
    }
    kT[tb + (t & 63) * DP + (d ^ ((t & 7) << 3))] = kv;
    vT[tb + d * 64 + ((t & 63) ^ ((d & 7) << 3))] = (f16)0.f;
}

// ---------------- B^T GEMM: C[m,n] = sum_k A[m,k]*B[n,k], f16 in / f32 acc --
// K-loop fixed at 19 x 64 = 1216 (inputs zero-padded; mode 3 relies on zero
// B-columns to neutralize the 16-element row overrun of lda=1200 A reads).
// LDS tiles are XOR-swizzled (rule #21: permuted gload SOURCE chunk + same XOR
// on the read) so fragment ds_read_b128 is ~2-way instead of 16-way banked.
// mode 0: Q -> (b,h,s,d) padded-128 linear
// mode 1: K -> [bh][tile][t&63][d ^ ((t&7)<<3)] swizzled 16KB tiles
// mode 2: V -> [bh][tile][d][(t&63) ^ ((d&7)<<3)] swizzled 16KB tiles
// mode 3: f32 row-major M x 1200 (final out)
__launch_bounds__(256)
__global__ void gemm_bt_kernel(const f16* __restrict__ A, int lda,
                               const f16* __restrict__ Bm,
                               f16* __restrict__ o16,
                               float* __restrict__ oF,
                               int mode) {
    __shared__ f16 As[128][64];
    __shared__ f16 Bs[128][64];

    const int tid  = threadIdx.x;
    const int lane = tid & 63, wave = tid >> 6;
    const int wm = wave >> 1, wn = wave & 1;     // 2x2 wave grid, 64x64 per wave
    const int n15 = lane & 15, g = lane >> 4;
    const int sx  = (n15 & 7) << 3;              // read-side XOR (row&7 == n15&7)
    const int brow = blockIdx.x * 128;
    const int bcol = blockIdx.y * 128;

    f32x4 acc[4][4];
#pragma unroll
    for (int i = 0; i < 4; ++i)
#pragma unroll
        for (int j = 0; j < 4; ++j)
            acc[i][j] = (f32x4){0.f, 0.f, 0.f, 0.f};

    const f16* Ab = A  + (size_t)brow * lda;
    const f16* Bb = Bm + (size_t)bcol * LDK;

    for (int kt = 0; kt < LDK / 64; ++kt) {      // 19
        const int k0 = kt << 6;
        __syncthreads();                         // all waves done reading prev tile
#pragma unroll
        for (int j = 0; j < 4; ++j) {
            const int c   = j * 256 + tid;       // 1024 chunks of 16B
            const int row = c >> 3;
            const int co  = ((c & 7) ^ (row & 7)) * 8;   // source-side permutation
            gload16(Ab + (size_t)row * lda + k0 + co, &As[0][0] + c * 8);
            gload16(Bb + (size_t)row * LDK + k0 + co, &Bs[0][0] + c * 8);
        }
        __syncthreads();                         // drains vmcnt(0) before barrier
#pragma unroll
        for (int kc = 0; kc < 2; ++kc) {
            f16x8 af[4], bf[4];
#pragma unroll
            for (int i = 0; i < 4; ++i)
                af[i] = *(const f16x8*)&As[wm * 64 + i * 16 + n15][(kc * 32 + g * 8) ^ sx];
#pragma unroll
            for (int i = 0; i < 4; ++i)
                bf[i] = *(const f16x8*)&Bs[wn * 64 + i * 16 + n15][(kc * 32 + g * 8) ^ sx];
#pragma unroll
            for (int mi = 0; mi < 4; ++mi)
#pragma unroll
                for (int ni = 0; ni < 4; ++ni)
                    acc[mi][ni] = MFMA_F16(af[mi], bf[ni], acc[mi][ni]);
        }
    }

    // epilogue — C/D frag: row = 4*g + r, col = n15
#pragma unroll
    for (int mi = 0; mi < 4; ++mi) {
        const int m0 = brow + wm * 64 + mi * 16 + g * 4;   // 4-aligned
        const int b  = m0 >> 11;
        const int s0 = m0 & (Sc - 1);
#pragma unroll
        for (int ni = 0; ni < 4; ++ni) {
            const int n = bcol + wn * 64 + ni * 16 + n15;
            if (n >= HIDc) continue;
            if (mode == 0) {
                const int h = n / 100, d = n - h * 100;
                f16* dst = o16 + ((size_t)(b * Hc + h) * Sc + s0) * DP + d;
#pragma unroll
                for (int r = 0; r < 4; ++r)
                    dst[r * DP] = (f16)acc[mi][ni][r];
            } else if (mode == 1) {
                const int h = n / 100, d = n - h * 100;
                const size_t tb = ((size_t)(b * Hc + h) * NT + (s0 >> 6)) * TE;
#pragma unroll
                for (int r = 0; r < 4; ++r) {
                    const int t = s0 + r;                  // same tile for r=0..3
                    o16[tb + (t & 63) * DP + (d ^ ((t & 7) << 3))] = (f16)acc[mi][ni][r];
                }
            } else if (mode == 2) {
                const int h = n / 100, d = n - h * 100;
                const size_t tb = ((size_t)(b * Hc + h) * NT + (s0 >> 6)) * TE;
                f16x4 pk;
#pragma unroll
                for (int r = 0; r < 4; ++r) pk[r] = (f16)acc[mi][ni][r];
                *(f16x4*)(o16 + tb + d * 64 + ((s0 & 63) ^ ((d & 7) << 3))) = pk;
            } else {
                float* dst = oF + (size_t)m0 * HIDc + n;
#pragma unroll
                for (int r = 0; r < 4; ++r)
                    dst[r * HIDc] = acc[mi][ni][r];
            }
        }
    }
}

// ---------------- fused flash attention (swapped-operand, log2 domain) -------
// grid (16, 48). 4 waves/block, 32 q-rows each. Single K/V LDS buffers with
// POST-USE issue + counted vmcnt(4): K(t+1) issued after the post-QK barrier
// (hidden under softmax+PV), V(t+1) after the post-PV barrier (hidden under
// next QK+softmax). Never drains vmcnt to 0 mid-loop. 48 KB LDS -> 3 blk/CU.
__launch_bounds__(256)
__global__ void attn_kernel(const f16* __restrict__ Qp, const f16* __restrict__ KpT,
                            const f16* __restrict__ VpT, const int* __restrict__ lidx,
                            f16* __restrict__ outp) {
    __shared__ f16 Kl[64][128];        // 16 KB, swizzled
    __shared__ f16 Vl[128][64];        // 16 KB, swizzled
    __shared__ f16 Pl[4][32][64];      // 16 KB, per-wave, swizzled

    const int tid  = threadIdx.x;
    const int lane = tid & 63, wave = tid >> 6;
    const int n15 = lane & 15, g = lane >> 4;
    const int sx  = (n15 & 7) << 3;    // shared XOR swizzle term
    const int bh = blockIdx.y;
    const int qr0 = blockIdx.x * 128 + wave * 32;

    // log2-domain scale: exp(s*10/(L+1)) == exp2(s*10*log2e/(L+1))
    const float scale = 10.f * 1.44269504f / (float)(lidx[0] + 1);

    // hoist Q (32 rows x 128 d) into registers, pre-scaled
    const f16* Qb = Qp + ((size_t)bh * Sc + qr0) * DP;
    f16x8 qreg[2][4];
#pragma unroll
    for (int qf = 0; qf < 2; ++qf)
#pragma unroll
        for (int kc = 0; kc < 4; ++kc) {
            f16x8 v = *(const f16x8*)(Qb + (qf * 16 + n15) * DP + kc * 32 + g * 8);
#pragma unroll
            for (int e = 0; e < 8; ++e)
                v[e] = (f16)((float)v[e] * scale);
            qreg[qf][kc] = v;
        }

    float m_run[2] = {-1e30f, -1e30f};
    float l_run[2] = {0.f, 0.f};
    f32x4 accO[2][7];                  // O^T: d = df*16 + g*4 + r, q = n15
#pragma unroll
    for (int qf = 0; qf < 2; ++qf)
#pragma unroll
        for (int df = 0; df < 7; ++df)
            accO[qf][df] = (f32x4){0.f, 0.f, 0.f, 0.f};

    const f16* Kbase = KpT + (size_t)bh * NT * TE;
    const f16* Vbase = VpT + (size_t)bh * NT * TE;
    f16* KlB = &Kl[0][0];
    f16* VlB = &Vl[0][0];

    // prologue: issue K0 (4 gloads) then V0 (4 gloads); queue = [K 4, V 4]
#pragma unroll
    for (int j = 0; j < 4; ++j) {
        const int c8 = (j * 256 + tid) * 8;
        gload16(Kbase + c8, KlB + c8);
    }
#pragma unroll
    for (int j = 0; j < 4; ++j) {
        const int c8 = (j * 256 + tid) * 8;
        gload16(Vbase + c8, VlB + c8);
    }

    for (int tile = 0; tile < NT; ++tile) {
        const bool more = (tile + 1 < NT);

        // (a) wait K(t) [queue: K(t) 4, V(t) 4 -> vmcnt(4)], sync
        asm volatile("s_waitcnt vmcnt(4)" ::: "memory");
        __builtin_amdgcn_s_barrier();
        __builtin_amdgcn_sched_barrier(0);

        // (b) S^T = K Q^T: sc[qf][tf], lane holds q=n15, t=tf*16+g*4+r
        f32x4 sc[2][4];
#pragma unroll
        for (int qf = 0; qf < 2; ++qf)
#pragma unroll
            for (int tf = 0; tf < 4; ++tf)
                sc[qf][tf] = (f32x4){0.f, 0.f, 0.f, 0.f};
        __builtin_amdgcn_s_setprio(1);
#pragma unroll
        for (int kc = 0; kc < 4; ++kc) {
            f16x8 kf[4];
#pragma unroll
            for (int tf = 0; tf < 4; ++tf)
                kf[tf] = *(const f16x8*)&Kl[tf * 16 + n15][(kc * 32 + g * 8) ^ sx];
#pragma unroll
            for (int qf = 0; qf < 2; ++qf)
#pragma unroll
                for (int tf = 0; tf < 4; ++tf)
                    sc[qf][tf] = MFMA_F16(kf[tf], qreg[qf][kc], sc[qf][tf]);
        }
        __builtin_amdgcn_s_setprio(0);

        // (c) all waves done reading Kl -> issue K(t+1) under softmax+PV
        asm volatile("s_waitcnt lgkmcnt(0)" ::: "memory");
        __builtin_amdgcn_s_barrier();
        __builtin_amdgcn_sched_barrier(0);
        if (more) {
            const f16* Kn = Kbase + (size_t)(tile + 1) * TE;
#pragma unroll
            for (int j = 0; j < 4; ++j) {
                const int c8 = (j * 256 + tid) * 8;
                gload16(Kn + c8, KlB + c8);
            }
        }

        // softmax: tile max per q (lane-local 16 vals + 2 shfl)
        float tmax[2];
#pragma unroll
        for (int qf = 0; qf < 2; ++qf) {
            float m0 = fmaxf(fmaxf(sc[qf][0][0], sc[qf][0][1]), fmaxf(sc[qf][0][2], sc[qf][0][3]));
#pragma unroll
            for (int tf = 1; tf < 4; ++tf)
                m0 = fmaxf(m0, fmaxf(fmaxf(sc[qf][tf][0], sc[qf][tf][1]),
                                     fmaxf(sc[qf][tf][2], sc[qf][tf][3])));
            m0 = fmaxf(m0, __shfl_xor(m0, 16));
            m0 = fmaxf(m0, __shfl_xor(m0, 32));
            tmax[qf] = m0;
        }

        // defer-max (T13): rescale only when a q exceeds its running max by >8
        if (__any((tmax[0] > m_run[0] + 8.f) || (tmax[1] > m_run[1] + 8.f))) {
#pragma unroll
            for (int qf = 0; qf < 2; ++qf) {
                const float mn = fmaxf(m_run[qf], tmax[qf]);
                const float al = exp2f(m_run[qf] - mn);
                m_run[qf] = mn;
                l_run[qf] *= al;
#pragma unroll
                for (int df = 0; df < 7; ++df) {
                    accO[qf][df][0] *= al; accO[qf][df][1] *= al;
                    accO[qf][df][2] *= al; accO[qf][df][3] *= al;
                }
            }
        }

        // P = exp2(s - m), row-sum, pack to per-wave LDS (swizzled b64)
#pragma unroll
        for (int qf = 0; qf < 2; ++qf) {
            float ps = 0.f;
#pragma unroll
            for (int tf = 0; tf < 4; ++tf) {
                f16x4 pk;
#pragma unroll
                for (int r = 0; r < 4; ++r) {
                    const float p = exp2f(sc[qf][tf][r] - m_run[qf]);
                    ps += p;
                    pk[r] = (f16)p;
                }
                *(f16x4*)&Pl[wave][qf * 16 + n15][(tf * 16 + g * 4) ^ sx] = pk;
            }
            ps += __shfl_xor(ps, 16);
            ps += __shfl_xor(ps, 32);
            l_run[qf] += ps;
        }

        // (d) wait V(t) [queue: V(t) 4, K(t+1) 4 -> vmcnt(4); last tile: 0]
        if (more) asm volatile("s_waitcnt vmcnt(4)" ::: "memory");
        else      asm volatile("s_waitcnt vmcnt(0)" ::: "memory");
        __builtin_amdgcn_s_barrier();
        __builtin_amdgcn_sched_barrier(0);

        // (e) O^T += V^T P^T; B-frag for block qf = P rows qf*16 + n15
        __builtin_amdgcn_s_setprio(1);
#pragma unroll
        for (int kc = 0; kc < 2; ++kc) {
            f16x8 pa[2];
#pragma unroll
            for (int qf = 0; qf < 2; ++qf)
                pa[qf] = *(const f16x8*)&Pl[wave][qf * 16 + n15][(kc * 32 + g * 8) ^ sx];
#pragma unroll
            for (int df = 0; df < 7; ++df) {
                const f16x8 vb = *(const f16x8*)&Vl[df * 16 + n15][(kc * 32 + g * 8) ^ sx];
#pragma unroll
                for (int qf = 0; qf < 2; ++qf)
                    accO[qf][df] = MFMA_F16(vb, pa[qf], accO[qf][df]);
            }
        }
        __builtin_amdgcn_s_setprio(0);

        // all waves done reading Vl -> issue V(t+1) under next QK+softmax
        asm volatile("s_waitcnt lgkmcnt(0)" ::: "memory");
        __builtin_amdgcn_s_barrier();
        __builtin_amdgcn_sched_barrier(0);
        if (more) {
            const f16* Vn = Vbase + (size_t)(tile + 1) * TE;
#pragma unroll
            for (int j = 0; j < 4; ++j) {
                const int c8 = (j * 256 + tid) * 8;
                gload16(Vn + c8, VlB + c8);
            }
        }
    }

    // epilogue: lane holds O[q=n15][d=df*16+g*4+r] -> packed f16x4 stores
#pragma unroll
    for (int qf = 0; qf < 2; ++qf) {
        const float rl = 1.f / l_run[qf];
        const int qrow = qr0 + qf * 16 + n15;
#pragma unroll
        for (int df = 0; df < 7; ++df) {
            const int d0 = df * 16 + g * 4;
            if (d0 < Dc) {
                f16x4 o;
#pragma unroll
                for (int r = 0; r < 4; ++r)
                    o[r] = (f16)(accO[qf][df][r] * rl);
                *(f16x4*)(outp + ((size_t)bh * Sc + qrow) * Dc + d0) = o;
            }
        }
    }
}

// ---------------- launcher ----------------
extern "C" void kernel_launch(void* const* d_in, const int* in_sizes, int n_in,
                              void* d_out, int out_size, void* d_ws, size_t ws_size,
                              hipStream_t stream) {
    const float* x     = (const float*)d_in[0];
    const float* alibi = (const float*)d_in[1];
    const float* amask = (const float*)d_in[2];
    const float* wq    = (const float*)d_in[3];
    const float* wk    = (const float*)d_in[4];
    const float* wv    = (const float*)d_in[5];
    const float* wo    = (const float*)d_in[6];
    const int*   lidx  = (const int*)d_in[7];
    float* out = (float*)d_out;

    char* p = (char*)d_ws;
    auto carve = [&](size_t bytes) {
        char* q = p;
        p += (bytes + 255) & ~size_t(255);
        return q;
    };
    f16* x16  = (f16*)carve((size_t)(Bc * Sc) * LDK * 2);        // 8192 x 1216
    f16* wq16 = (f16*)carve((size_t)NWP * LDK * 2);              // 1280 x 1216
    f16* wk16 = (f16*)carve((size_t)NWP * LDK * 2);
    f16* wv16 = (f16*)carve((size_t)NWP * LDK * 2);
    f16* wo16 = (f16*)carve((size_t)NWP * LDK * 2);
    f16* QpL  = (f16*)carve((size_t)BH * Sc * DP * 2);           // (bh,s,128) linear
    f16* KpT  = (f16*)carve((size_t)BH * NT * TE * 2);           // swizzled tiles
    f16* VpT  = (f16*)carve((size_t)BH * NT * TE * 2);           // swizzled tiles
    f16* comb = (f16*)carve((size_t)BH * Sc * Dc * 2 + 4096);    // + overrun slack

    // 1) fp16 conversions (+ zero pads), x4-vectorized
    {
        int total4 = Bc * Sc * LDK / 4;
        cvt_pad4_kernel<<<(total4 + 255) / 256, 256, 0, stream>>>(x, x16, Bc * Sc, HIDc, LDK, total4);
    }
    {
        int total4 = NWP * LDK / 4;
        int nb = (total4 + 255) / 256;
        cvt_pad4_kernel<<<nb, 256, 0, stream>>>(wq, wq16, HIDc, HIDc, LDK, total4);
        cvt_pad4_kernel<<<nb, 256, 0, stream>>>(wk, wk16, HIDc, HIDc, LDK, total4);
        cvt_pad4_kernel<<<nb, 256, 0, stream>>>(wv, wv16, HIDc, HIDc, LDK, total4);
        cvt_pad4_kernel<<<nb, 256, 0, stream>>>(wo, wo16, HIDc, HIDc, LDK, total4);
    }
    // 2) pads of Q/K/V; K d=100 carries the alibi+mask bias (log2-domain trick)
    {
        int total = BH * Sc * (DP - Dc);
        pad_bufs_kernel<<<(total + 255) / 256, 256, 0, stream>>>(QpL, KpT, VpT, alibi, amask, lidx);
    }
    // 3) projections
    dim3 gg(64, 10);
    gemm_bt_kernel<<<gg, 256, 0, stream>>>(x16, LDK, wq16, QpL, nullptr, 0);
    gemm_bt_kernel<<<gg, 256, 0, stream>>>(x16, LDK, wk16, KpT, nullptr, 1);
    gemm_bt_kernel<<<gg, 256, 0, stream>>>(x16, LDK, wv16, VpT, nullptr, 2);
    // 4) fused attention
    attn_kernel<<<dim3(Sc / 128, BH), 256, 0, stream>>>(QpL, KpT, VpT, lidx, comb);
    // 5) output projection (reads comb linearly as 8192 x 1200; 16-elem row
    //    overrun lands on wo16's zero K-columns)
    gemm_bt_kernel<<<gg, 256, 0, stream>>>(comb, HIDc, wo16, nullptr, out, 3);
}

// Round 6
// 327.991 us; speedup vs baseline: 1.3321x; 1.2427x over previous
//
#include <hip/hip_runtime.h>

typedef _Float16 f16;
typedef __attribute__((ext_vector_type(8)))  _Float16 f16x8;
typedef __attribute__((ext_vector_type(4)))  _Float16 f16x4;
typedef __attribute__((ext_vector_type(4)))  float    f32x4;
typedef __attribute__((ext_vector_type(16))) float    f32x16;
typedef __attribute__((ext_vector_type(4)))  int      i32x4;

#define MFMA_F16(a,b,c) __builtin_amdgcn_mfma_f32_16x16x32_f16((a),(b),(c),0,0,0)
#define MFMA32(a,b,c)   __builtin_amdgcn_mfma_f32_32x32x16_f16((a),(b),(c),0,0,0)

// problem constants
constexpr int Bc   = 4;
constexpr int Sc   = 2048;
constexpr int Hc   = 12;
constexpr int Dc   = 100;
constexpr int HIDc = 1200;
constexpr int BH   = Bc * Hc;    // 48
constexpr int DP   = 128;        // padded head dim (dim 100 carries the bias trick)
constexpr int LDK  = 1216;       // padded inner dim for x16/w16 (19 * 64)
constexpr int NWP  = 1280;       // padded row count for w16 (N-tile overrun)
constexpr int KVT  = 64;         // kv tile length
constexpr int NT   = Sc / KVT;   // 32 tiles per (b,h)
constexpr int TE   = KVT * DP;   // 8192 elems per K or V tile (16 KB)

// async global->LDS, 16B per lane (linear dest = base + lane*16)
typedef const __attribute__((address_space(1))) void GV;
typedef __attribute__((address_space(3))) void LV;
__device__ __forceinline__ void gload16(const f16* g, f16* l) {
    __builtin_amdgcn_global_load_lds((GV*)g, (LV*)l, 16, 0, 0);
}

// ---------------- fp32 -> fp16 convert with zero padding (x4 vectorized) ----
__global__ void cvt_pad4_kernel(const float* __restrict__ src, f16* __restrict__ dst,
                                int srcR, int srcC, int dstC, int total4) {
    int i = blockIdx.x * 256 + threadIdx.x;
    if (i >= total4) return;
    int idx = i * 4;
    int r = idx / dstC, c = idx - r * dstC;     // dstC % 4 == 0 -> no row straddle
    f16x4 o;
    if (r < srcR && c + 3 < srcC) {
        float4 v = *(const float4*)(src + r * srcC + c);
        o[0] = (f16)v.x; o[1] = (f16)v.y; o[2] = (f16)v.z; o[3] = (f16)v.w;
    } else {
#pragma unroll
        for (int e = 0; e < 4; ++e) {
            float vv = (r < srcR && c + e < srcC) ? src[r * srcC + c + e] : 0.f;
            o[e] = (f16)vv;
        }
    }
    *(f16x4*)(dst + idx) = o;
}

// pads: Q linear d=[100,128) (1 at d=100, 0 else); K tiled-swizzled d=[100,128)
// (bias at d=100, 0 else); V tiled-swizzled rows d=[100,128) zero.
// bias: Q[s,100]=1 (scaled by 10*log2e/(L+1) in attn), K[t,100]=alibi/10+mask*(L+1)/10
__global__ void pad_bufs_kernel(f16* __restrict__ q, f16* __restrict__ kT, f16* __restrict__ vT,
                                const float* __restrict__ alibi, const float* __restrict__ amask,
                                const int* __restrict__ lidx) {
    int i = blockIdx.x * 256 + threadIdx.x;
    constexpr int PADW = DP - Dc;              // 28
    if (i >= BH * Sc * PADW) return;
    int dd = i % PADW;
    int rs = i / PADW;                          // bh*S + t
    int d  = Dc + dd;
    int bh = rs >> 11, t = rs & (Sc - 1);
    int b  = bh / Hc;
    q[rs * DP + d] = (d == Dc) ? (f16)1.0f : (f16)0.f;
    const size_t tb = ((size_t)bh * NT + (t >> 6)) * TE;
    f16 kv = (f16)0.f;
    if (d == Dc) {
        float bias = alibi[rs] * 0.1f + amask[b * Sc + t] * ((float)(lidx[0] + 1) * 0.1f);
        kv = (f16)bias;
    }
    kT[tb + (t & 63) * DP + (d ^ ((t & 15) << 3))] = kv;     // 4-bit XOR
    vT[tb + d * 64 + ((t & 63) ^ ((d & 7) << 3))] = (f16)0.f;
}

// ---------------- B^T GEMM: C[m,n] = sum_k A[m,k]*B[n,k], f16 in / f32 acc --
// K-loop fixed at 19 x 64 = 1216 (inputs zero-padded; mode 1 relies on zero
// B-columns to neutralize the 16-element row overrun of lda=1200 A reads).
// LDS tiles XOR-swizzled (rule #21: permuted gload SOURCE chunk + same XOR read).
// mode 0: fused QKV. B = [wq16; wk16; wv16] (contiguous, 1280-row sections).
//         n -> which = n/1280: 0 -> Q linear (b,h,s,d)pad128; 1 -> K swizzled
//         tiles [t][d^((t&15)<<3)]; 2 -> V swizzled tiles [d][(t&63)^((d&7)<<3)]
// mode 1: f32 row-major M x 1200 (final out)
__launch_bounds__(256)
__global__ void gemm_bt_kernel(const f16* __restrict__ A, int lda,
                               const f16* __restrict__ Bm,
                               f16* __restrict__ outQ,
                               f16* __restrict__ outK,
                               f16* __restrict__ outV,
                               float* __restrict__ oF,
                               int mode) {
    __shared__ f16 As[128][64];
    __shared__ f16 Bs[128][64];

    const int tid  = threadIdx.x;
    const int lane = tid & 63, wave = tid >> 6;
    const int wm = wave >> 1, wn = wave & 1;     // 2x2 wave grid, 64x64 per wave
    const int n15 = lane & 15, g = lane >> 4;
    const int sx  = (n15 & 7) << 3;              // read-side XOR (row&7 == n15&7)
    const int brow = blockIdx.x * 128;
    const int bcol = blockIdx.y * 128;

    f32x4 acc[4][4];
#pragma unroll
    for (int i = 0; i < 4; ++i)
#pragma unroll
        for (int j = 0; j < 4; ++j)
            acc[i][j] = (f32x4){0.f, 0.f, 0.f, 0.f};

    const f16* Ab = A  + (size_t)brow * lda;
    const f16* Bb = Bm + (size_t)bcol * LDK;

    for (int kt = 0; kt < LDK / 64; ++kt) {      // 19
        const int k0 = kt << 6;
        __syncthreads();                         // all waves done reading prev tile
#pragma unroll
        for (int j = 0; j < 4; ++j) {
            const int c   = j * 256 + tid;       // 1024 chunks of 16B
            const int row = c >> 3;
            const int co  = ((c & 7) ^ (row & 7)) * 8;   // source-side permutation
            gload16(Ab + (size_t)row * lda + k0 + co, &As[0][0] + c * 8);
            gload16(Bb + (size_t)row * LDK + k0 + co, &Bs[0][0] + c * 8);
        }
        __syncthreads();                         // drains vmcnt(0) before barrier
#pragma unroll
        for (int kc = 0; kc < 2; ++kc) {
            f16x8 af[4], bf[4];
#pragma unroll
            for (int i = 0; i < 4; ++i)
                af[i] = *(const f16x8*)&As[wm * 64 + i * 16 + n15][(kc * 32 + g * 8) ^ sx];
#pragma unroll
            for (int i = 0; i < 4; ++i)
                bf[i] = *(const f16x8*)&Bs[wn * 64 + i * 16 + n15][(kc * 32 + g * 8) ^ sx];
#pragma unroll
            for (int mi = 0; mi < 4; ++mi)
#pragma unroll
                for (int ni = 0; ni < 4; ++ni)
                    acc[mi][ni] = MFMA_F16(af[mi], bf[ni], acc[mi][ni]);
        }
    }

    // epilogue — C/D frag: row = 4*g + r, col = n15
#pragma unroll
    for (int mi = 0; mi < 4; ++mi) {
        const int m0 = brow + wm * 64 + mi * 16 + g * 4;   // 4-aligned
        const int b  = m0 >> 11;
        const int s0 = m0 & (Sc - 1);
#pragma unroll
        for (int ni = 0; ni < 4; ++ni) {
            const int n = bcol + wn * 64 + ni * 16 + n15;
            if (mode == 1) {
                if (n >= HIDc) continue;
                float* dst = oF + (size_t)m0 * HIDc + n;
#pragma unroll
                for (int r = 0; r < 4; ++r)
                    dst[r * HIDc] = acc[mi][ni][r];
            } else {
                const int which = (n >= 2560) ? 2 : (n >= 1280 ? 1 : 0);
                const int nn = n - which * 1280;
                if (nn >= HIDc) continue;
                const int h = nn / 100, d = nn - h * 100;
                if (which == 0) {
                    f16* dst = outQ + ((size_t)(b * Hc + h) * Sc + s0) * DP + d;
#pragma unroll
                    for (int r = 0; r < 4; ++r)
                        dst[r * DP] = (f16)acc[mi][ni][r];
                } else if (which == 1) {
                    const size_t tb = ((size_t)(b * Hc + h) * NT + (s0 >> 6)) * TE;
#pragma unroll
                    for (int r = 0; r < 4; ++r) {
                        const int t = s0 + r;              // same tile for r=0..3
                        outK[tb + (t & 63) * DP + (d ^ ((t & 15) << 3))] = (f16)acc[mi][ni][r];
                    }
                } else {
                    const size_t tb = ((size_t)(b * Hc + h) * NT + (s0 >> 6)) * TE;
                    f16x4 pk;
#pragma unroll
                    for (int r = 0; r < 4; ++r) pk[r] = (f16)acc[mi][ni][r];
                    *(f16x4*)(outV + tb + d * 64 + ((s0 & 63) ^ ((d & 7) << 3))) = pk;
                }
            }
        }
    }
}

// ---------------- fused flash attention, 32x32 MFMA / in-register P ----------
// grid 768 1-D, XCD-swizzled: bh = (bid&7)*6 + (bid>>3)/16 -> each (b,h)'s 16
// q-tiles live on ONE XCD (K/V L2-resident per XCD). 4 waves/block, 32 q each.
// Lane holds q = lane&31; softmax state is a single scalar (m,l) per lane.
// P never touches LDS: cvt_pkrtz + v_permlane32_swap_b32 build PV B-fragments.
__launch_bounds__(256, 3)
__global__ void attn_kernel(const f16* __restrict__ Qp, const f16* __restrict__ KpT,
                            const f16* __restrict__ VpT, const int* __restrict__ lidx,
                            f16* __restrict__ outp) {
    __shared__ f16 Kl[64][128];        // 16 KB, 4-bit swizzle
    __shared__ f16 Vl[128][64];        // 16 KB, 3-bit swizzle

    const int tid  = threadIdx.x;
    const int lane = tid & 63, wave = tid >> 6;
    const int l31 = lane & 31, h = lane >> 5;
    const int sxk = (l31 & 15) << 3;   // K read XOR ((t&15) == (l31&15))
    const int sxv = (l31 & 7) << 3;    // V read XOR ((d&7) == (l31&7))

    const int bid = blockIdx.x;
    const int bh  = (bid & 7) * 6 + ((bid >> 3) >> 4);
    const int qt  = (bid >> 3) & 15;
    const int qr0 = qt * 128 + wave * 32;

    // log2-domain scale: exp(s*10/(L+1)) == exp2(s*10*log2e/(L+1))
    const float scale = 10.f * 1.44269504f / (float)(lidx[0] + 1);

    // Q rows in regs: qreg[step] elem e = Q[qr0+l31][step*16 + h*8 + e], pre-scaled
    const f16* Qb = Qp + ((size_t)bh * Sc + qr0 + l31) * DP + h * 8;
    f16x8 qreg[8];
#pragma unroll
    for (int st = 0; st < 8; ++st) {
        f16x8 v = *(const f16x8*)(Qb + st * 16);
#pragma unroll
        for (int e = 0; e < 8; ++e)
            v[e] = (f16)((float)v[e] * scale);
        qreg[st] = v;
    }

    float m_run = -1e30f, l_run = 0.f;
    f32x16 accO[4];                    // O^T block db: d = db*32+(reg&3)+8*(reg>>2)+4h, q=l31
#pragma unroll
    for (int db = 0; db < 4; ++db)
#pragma unroll
        for (int i = 0; i < 16; ++i)
            accO[db][i] = 0.f;

    const f16* Kbase = KpT + (size_t)bh * NT * TE;
    const f16* Vbase = VpT + (size_t)bh * NT * TE;
    f16* KlB = &Kl[0][0];
    f16* VlB = &Vl[0][0];

    // prologue: issue K0 then V0; queue = [K 4, V 4]
#pragma unroll
    for (int j = 0; j < 4; ++j) gload16(Kbase + (j * 256 + tid) * 8, KlB + (j * 256 + tid) * 8);
#pragma unroll
    for (int j = 0; j < 4; ++j) gload16(Vbase + (j * 256 + tid) * 8, VlB + (j * 256 + tid) * 8);

    for (int tile = 0; tile < NT; ++tile) {
        const bool more = (tile + 1 < NT);

        // (a) K(t) ready [K 4 + V 4 in flight -> vmcnt(4)]
        asm volatile("s_waitcnt vmcnt(4)" ::: "memory");
        __builtin_amdgcn_s_barrier();
        __builtin_amdgcn_sched_barrier(0);

        // (b) S^T = K Q^T: sc0/sc1 = t-blocks; lane: q=l31, t = tb*32+(reg&3)+8*(reg>>2)+4h
        f32x16 sc0, sc1;
#pragma unroll
        for (int i = 0; i < 16; ++i) { sc0[i] = 0.f; sc1[i] = 0.f; }
        __builtin_amdgcn_s_setprio(1);
#pragma unroll
        for (int st = 0; st < 8; ++st) {
            const int col = (st * 16 + h * 8) ^ sxk;
            f16x8 kf0 = *(const f16x8*)&Kl[l31][col];
            f16x8 kf1 = *(const f16x8*)&Kl[32 + l31][col];
            sc0 = MFMA32(kf0, qreg[st], sc0);
            sc1 = MFMA32(kf1, qreg[st], sc1);
        }
        __builtin_amdgcn_s_setprio(0);

        // (c) Kl free -> issue K(t+1) under softmax
        asm volatile("s_waitcnt lgkmcnt(0)" ::: "memory");
        __builtin_amdgcn_sched_barrier(0);
        __builtin_amdgcn_s_barrier();
        if (more) {
            const f16* Kn = Kbase + (size_t)(tile + 1) * TE;
#pragma unroll
            for (int j = 0; j < 4; ++j) gload16(Kn + (j * 256 + tid) * 8, KlB + (j * 256 + tid) * 8);
        }

        // softmax (fully lane-local + one shfl): tile max over 64 t for own q
        float tm = sc0[0];
#pragma unroll
        for (int i = 1; i < 16; ++i) tm = fmaxf(tm, sc0[i]);
#pragma unroll
        for (int i = 0; i < 16; ++i) tm = fmaxf(tm, sc1[i]);
        tm = fmaxf(tm, __shfl_xor(tm, 32));

        // defer-max (T13): rescale only when max grew by >8 (log2 domain)
        if (__any(tm > m_run + 8.f)) {
            const float mn = fmaxf(m_run, tm);
            const float al = exp2f(m_run - mn);
            m_run = mn;
            l_run *= al;
#pragma unroll
            for (int db = 0; db < 4; ++db) accO[db] *= al;
        }

        // P = exp2(s - m) in place; row-sum over all 64 t
        float ps = 0.f;
#pragma unroll
        for (int i = 0; i < 16; ++i) { sc0[i] = exp2f(sc0[i] - m_run); ps += sc0[i]; }
#pragma unroll
        for (int i = 0; i < 16; ++i) { sc1[i] = exp2f(sc1[i] - m_run); ps += sc1[i]; }
        ps += __shfl_xor(ps, 32);
        l_run += ps;

        // pack P -> PV B-frags (pa[kk], kk = tb*2+ks): cvt_pkrtz + permlane32_swap.
        // B-frag[kk] lane(h): dw0/dw1 = {r0..r3} of (c=2ks+h, h_src=0),
        //                     dw2/dw3 = {r0..r3} of (c=2ks+h, h_src=1).
        // swap(P_{2ks}.dw, P_{2ks+1}.dw) -> first' = dw0-part, second' = dw2-part.
        f16x8 pa[4];
        {
            int e0[4], e1[4];
#pragma unroll
            for (int c = 0; c < 4; ++c) {
                auto lo = __builtin_amdgcn_cvt_pkrtz(sc0[4 * c + 0], sc0[4 * c + 1]);
                auto hi = __builtin_amdgcn_cvt_pkrtz(sc0[4 * c + 2], sc0[4 * c + 3]);
                e0[c] = __builtin_bit_cast(int, lo);
                e1[c] = __builtin_bit_cast(int, hi);
            }
#pragma unroll
            for (int ks = 0; ks < 2; ++ks) {
                int a0 = e0[2 * ks], b0 = e0[2 * ks + 1];
                int a1 = e1[2 * ks], b1 = e1[2 * ks + 1];
                asm("v_permlane32_swap_b32 %0, %1" : "+v"(a0), "+v"(b0));
                asm("v_permlane32_swap_b32 %0, %1" : "+v"(a1), "+v"(b1));
                i32x4 w = {a0, a1, b0, b1};
                pa[ks] = __builtin_bit_cast(f16x8, w);
            }
#pragma unroll
            for (int c = 0; c < 4; ++c) {
                auto lo = __builtin_amdgcn_cvt_pkrtz(sc1[4 * c + 0], sc1[4 * c + 1]);
                auto hi = __builtin_amdgcn_cvt_pkrtz(sc1[4 * c + 2], sc1[4 * c + 3]);
                e0[c] = __builtin_bit_cast(int, lo);
                e1[c] = __builtin_bit_cast(int, hi);
            }
#pragma unroll
            for (int ks = 0; ks < 2; ++ks) {
                int a0 = e0[2 * ks], b0 = e0[2 * ks + 1];
                int a1 = e1[2 * ks], b1 = e1[2 * ks + 1];
                asm("v_permlane32_swap_b32 %0, %1" : "+v"(a0), "+v"(b0));
                asm("v_permlane32_swap_b32 %0, %1" : "+v"(a1), "+v"(b1));
                i32x4 w = {a0, a1, b0, b1};
                pa[2 + ks] = __builtin_bit_cast(f16x8, w);
            }
        }

        // (d) V(t) ready [V 4 + K(t+1) 4 -> vmcnt(4); last tile 0]
        if (more) asm volatile("s_waitcnt vmcnt(4)" ::: "memory");
        else      asm volatile("s_waitcnt vmcnt(0)" ::: "memory");
        __builtin_amdgcn_s_barrier();
        __builtin_amdgcn_sched_barrier(0);

        // (e) O^T += V^T P^T: A = V^T[d][t] from Vl, B = pa
        __builtin_amdgcn_s_setprio(1);
#pragma unroll
        for (int kk = 0; kk < 4; ++kk) {
            const int col = (kk * 16 + h * 8) ^ sxv;
#pragma unroll
            for (int db = 0; db < 4; ++db) {
                f16x8 vf = *(const f16x8*)&Vl[db * 32 + l31][col];
                accO[db] = MFMA32(vf, pa[kk], accO[db]);
            }
        }
        __builtin_amdgcn_s_setprio(0);

        // Vl free -> issue V(t+1) under next QK+softmax
        asm volatile("s_waitcnt lgkmcnt(0)" ::: "memory");
        __builtin_amdgcn_sched_barrier(0);
        __builtin_amdgcn_s_barrier();
        if (more) {
            const f16* Vn = Vbase + (size_t)(tile + 1) * TE;
#pragma unroll
            for (int j = 0; j < 4; ++j) gload16(Vn + (j * 256 + tid) * 8, VlB + (j * 256 + tid) * 8);
        }
    }

    // epilogue: lane holds O[q=l31][d = db*32 + 8c + 4h + r] -> f16x4 stores
    const float rl = 1.f / l_run;
    f16* orow = outp + ((size_t)bh * Sc + qr0 + l31) * Dc;
#pragma unroll
    for (int db = 0; db < 4; ++db) {
#pragma unroll
        for (int c = 0; c < 4; ++c) {
            const int d0 = db * 32 + c * 8 + h * 4;
            if (d0 < Dc) {
                f16x4 o;
#pragma unroll
                for (int r = 0; r < 4; ++r)
                    o[r] = (f16)(accO[db][4 * c + r] * rl);
                *(f16x4*)(orow + d0) = o;
            }
        }
    }
}

// ---------------- launcher ----------------
extern "C" void kernel_launch(void* const* d_in, const int* in_sizes, int n_in,
                              void* d_out, int out_size, void* d_ws, size_t ws_size,
                              hipStream_t stream) {
    const float* x     = (const float*)d_in[0];
    const float* alibi = (const float*)d_in[1];
    const float* amask = (const float*)d_in[2];
    const float* wq    = (const float*)d_in[3];
    const float* wk    = (const float*)d_in[4];
    const float* wv    = (const float*)d_in[5];
    const float* wo    = (const float*)d_in[6];
    const int*   lidx  = (const int*)d_in[7];
    float* out = (float*)d_out;

    char* p = (char*)d_ws;
    auto carve = [&](size_t bytes) {
        char* q = p;
        p += (bytes + 255) & ~size_t(255);
        return q;
    };
    f16* x16  = (f16*)carve((size_t)(Bc * Sc) * LDK * 2);        // 8192 x 1216
    f16* wq16 = (f16*)carve((size_t)NWP * LDK * 2);              // 1280 x 1216 (wq/wk/wv contiguous!)
    f16* wk16 = (f16*)carve((size_t)NWP * LDK * 2);
    f16* wv16 = (f16*)carve((size_t)NWP * LDK * 2);
    f16* wo16 = (f16*)carve((size_t)NWP * LDK * 2);
    f16* QpL  = (f16*)carve((size_t)BH * Sc * DP * 2);           // (bh,s,128) linear
    f16* KpT  = (f16*)carve((size_t)BH * NT * TE * 2);           // swizzled tiles
    f16* VpT  = (f16*)carve((size_t)BH * NT * TE * 2);           // swizzled tiles
    f16* comb = (f16*)carve((size_t)BH * Sc * Dc * 2 + 4096);    // + overrun slack

    // 1) fp16 conversions (+ zero pads), x4-vectorized
    {
        int total4 = Bc * Sc * LDK / 4;
        cvt_pad4_kernel<<<(total4 + 255) / 256, 256, 0, stream>>>(x, x16, Bc * Sc, HIDc, LDK, total4);
    }
    {
        int total4 = NWP * LDK / 4;
        int nb = (total4 + 255) / 256;
        cvt_pad4_kernel<<<nb, 256, 0, stream>>>(wq, wq16, HIDc, HIDc, LDK, total4);
        cvt_pad4_kernel<<<nb, 256, 0, stream>>>(wk, wk16, HIDc, HIDc, LDK, total4);
        cvt_pad4_kernel<<<nb, 256, 0, stream>>>(wv, wv16, HIDc, HIDc, LDK, total4);
        cvt_pad4_kernel<<<nb, 256, 0, stream>>>(wo, wo16, HIDc, HIDc, LDK, total4);
    }
    // 2) pads of Q/K/V; K d=100 carries the alibi+mask bias (log2-domain trick)
    {
        int total = BH * Sc * (DP - Dc);
        pad_bufs_kernel<<<(total + 255) / 256, 256, 0, stream>>>(QpL, KpT, VpT, alibi, amask, lidx);
    }
    // 3) fused QKV projection: B = [wq16; wk16; wv16], N = 3840, grid 1920 blocks
    gemm_bt_kernel<<<dim3(64, 30), 256, 0, stream>>>(x16, LDK, wq16, QpL, KpT, VpT, nullptr, 0);
    // 4) fused attention (768 blocks, XCD-swizzled)
    attn_kernel<<<dim3(768), 256, 0, stream>>>(QpL, KpT, VpT, lidx, comb);
    // 5) output projection (reads comb linearly as 8192 x 1200; 16-elem row
    //    overrun lands on wo16's zero K-columns)
    gemm_bt_kernel<<<dim3(64, 10), 256, 0, stream>>>(comb, HIDc, wo16, nullptr, nullptr, nullptr, out, 1);
}

// Round 7
// 320.433 us; speedup vs baseline: 1.3636x; 1.0236x over previous
//
#include <hip/hip_runtime.h>

typedef _Float16 f16;
typedef __attribute__((ext_vector_type(8)))  _Float16 f16x8;
typedef __attribute__((ext_vector_type(4)))  _Float16 f16x4;
typedef __attribute__((ext_vector_type(4)))  float    f32x4;
typedef __attribute__((ext_vector_type(16))) float    f32x16;
typedef __attribute__((ext_vector_type(4)))  int      i32x4;

#define MFMA_F16(a,b,c) __builtin_amdgcn_mfma_f32_16x16x32_f16((a),(b),(c),0,0,0)
#define MFMA32(a,b,c)   __builtin_amdgcn_mfma_f32_32x32x16_f16((a),(b),(c),0,0,0)

// problem constants
constexpr int Bc   = 4;
constexpr int Sc   = 2048;
constexpr int Hc   = 12;
constexpr int Dc   = 100;
constexpr int HIDc = 1200;
constexpr int BH   = Bc * Hc;    // 48
constexpr int DP   = 128;        // padded head dim (dim 100 carries the bias trick)
constexpr int LDK  = 1216;       // padded inner dim for x16/w16 (19 * 64)
constexpr int NWP  = 1280;       // padded row count for w16 (N-tile overrun)
constexpr int KVT  = 64;         // kv tile length
constexpr int NT   = Sc / KVT;   // 32 tiles per (b,h)
constexpr int TE   = KVT * DP;   // 8192 elems per K or V tile (16 KB)

// async global->LDS, 16B per lane (linear dest = base + lane*16)
typedef const __attribute__((address_space(1))) void GV;
typedef __attribute__((address_space(3))) void LV;
__device__ __forceinline__ void gload16(const f16* g, f16* l) {
    __builtin_amdgcn_global_load_lds((GV*)g, (LV*)l, 16, 0, 0);
}

// ---------------- fp32 -> fp16 convert with zero padding (x4 vectorized) ----
__global__ void cvt_pad4_kernel(const float* __restrict__ src, f16* __restrict__ dst,
                                int srcR, int srcC, int dstC, int total4) {
    int i = blockIdx.x * 256 + threadIdx.x;
    if (i >= total4) return;
    int idx = i * 4;
    int r = idx / dstC, c = idx - r * dstC;     // dstC % 4 == 0 -> no row straddle
    f16x4 o;
    if (r < srcR && c + 3 < srcC) {
        float4 v = *(const float4*)(src + r * srcC + c);
        o[0] = (f16)v.x; o[1] = (f16)v.y; o[2] = (f16)v.z; o[3] = (f16)v.w;
    } else {
#pragma unroll
        for (int e = 0; e < 4; ++e) {
            float vv = (r < srcR && c + e < srcC) ? src[r * srcC + c + e] : 0.f;
            o[e] = (f16)vv;
        }
    }
    *(f16x4*)(dst + idx) = o;
}

// merged 4-weight convert: blockIdx.y selects (src,dst) pair; 1200x1200 -> 1280x1216
__global__ void cvt_w_kernel(const float* __restrict__ w0, const float* __restrict__ w1,
                             const float* __restrict__ w2, const float* __restrict__ w3,
                             f16* __restrict__ d0, f16* __restrict__ d1,
                             f16* __restrict__ d2, f16* __restrict__ d3, int total4) {
    int i = blockIdx.x * 256 + threadIdx.x;
    if (i >= total4) return;
    const float* src; f16* dst;
    switch (blockIdx.y) {
        case 0:  src = w0; dst = d0; break;
        case 1:  src = w1; dst = d1; break;
        case 2:  src = w2; dst = d2; break;
        default: src = w3; dst = d3; break;
    }
    int idx = i * 4;
    int r = idx / LDK, c = idx - r * LDK;
    f16x4 o;
    if (r < HIDc && c + 3 < HIDc) {
        float4 v = *(const float4*)(src + r * HIDc + c);
        o[0] = (f16)v.x; o[1] = (f16)v.y; o[2] = (f16)v.z; o[3] = (f16)v.w;
    } else {
#pragma unroll
        for (int e = 0; e < 4; ++e) {
            float vv = (r < HIDc && c + e < HIDc) ? src[r * HIDc + c + e] : 0.f;
            o[e] = (f16)vv;
        }
    }
    *(f16x4*)(dst + idx) = o;
}

// pads: Q linear d=[100,128) (1 at d=100, 0 else); K tiled-swizzled d=[100,128)
// (bias at d=100, 0 else); V tiled-swizzled rows d=[100,128) zero.
// bias: Q[s,100]=1 (scaled by 10*log2e/(L+1) in attn), K[t,100]=alibi/10+mask*(L+1)/10
__global__ void pad_bufs_kernel(f16* __restrict__ q, f16* __restrict__ kT, f16* __restrict__ vT,
                                const float* __restrict__ alibi, const float* __restrict__ amask,
                                const int* __restrict__ lidx) {
    int i = blockIdx.x * 256 + threadIdx.x;
    constexpr int PADW = DP - Dc;              // 28
    if (i >= BH * Sc * PADW) return;
    int dd = i % PADW;
    int rs = i / PADW;                          // bh*S + t
    int d  = Dc + dd;
    int bh = rs >> 11, t = rs & (Sc - 1);
    int b  = bh / Hc;
    q[rs * DP + d] = (d == Dc) ? (f16)1.0f : (f16)0.f;
    const size_t tb = ((size_t)bh * NT + (t >> 6)) * TE;
    f16 kv = (f16)0.f;
    if (d == Dc) {
        float bias = alibi[rs] * 0.1f + amask[b * Sc + t] * ((float)(lidx[0] + 1) * 0.1f);
        kv = (f16)bias;
    }
    kT[tb + (t & 63) * DP + (d ^ ((t & 15) << 3))] = kv;     // 4-bit XOR
    vT[tb + d * 64 + ((t & 63) ^ ((d & 7) << 3))] = (f16)0.f;
}

// ---------------- B^T GEMM: C[m,n] = sum_k A[m,k]*B[n,k], f16 in / f32 acc --
// K-loop fixed at 19 x 64 = 1216 (inputs zero-padded; mode 1 relies on zero
// B-columns to neutralize the 16-element row overrun of lda=1200 A reads).
// LDS tiles XOR-swizzled (rule #21: permuted gload SOURCE chunk + same XOR read).
// mode 0: fused QKV. B = [wq16; wk16; wv16] (contiguous, 1280-row sections).
// mode 1: f32 row-major M x 1200 (final out)
__launch_bounds__(256)
__global__ void gemm_bt_kernel(const f16* __restrict__ A, int lda,
                               const f16* __restrict__ Bm,
                               f16* __restrict__ outQ,
                               f16* __restrict__ outK,
                               f16* __restrict__ outV,
                               float* __restrict__ oF,
                               int mode) {
    __shared__ f16 As[128][64];
    __shared__ f16 Bs[128][64];

    const int tid  = threadIdx.x;
    const int lane = tid & 63, wave = tid >> 6;
    const int wm = wave >> 1, wn = wave & 1;     // 2x2 wave grid, 64x64 per wave
    const int n15 = lane & 15, g = lane >> 4;
    const int sx  = (n15 & 7) << 3;              // read-side XOR (row&7 == n15&7)
    const int brow = blockIdx.x * 128;
    const int bcol = blockIdx.y * 128;

    f32x4 acc[4][4];
#pragma unroll
    for (int i = 0; i < 4; ++i)
#pragma unroll
        for (int j = 0; j < 4; ++j)
            acc[i][j] = (f32x4){0.f, 0.f, 0.f, 0.f};

    const f16* Ab = A  + (size_t)brow * lda;
    const f16* Bb = Bm + (size_t)bcol * LDK;

    for (int kt = 0; kt < LDK / 64; ++kt) {      // 19
        const int k0 = kt << 6;
        __syncthreads();                         // all waves done reading prev tile
#pragma unroll
        for (int j = 0; j < 4; ++j) {
            const int c   = j * 256 + tid;       // 1024 chunks of 16B
            const int row = c >> 3;
            const int co  = ((c & 7) ^ (row & 7)) * 8;   // source-side permutation
            gload16(Ab + (size_t)row * lda + k0 + co, &As[0][0] + c * 8);
            gload16(Bb + (size_t)row * LDK + k0 + co, &Bs[0][0] + c * 8);
        }
        __syncthreads();                         // drains vmcnt(0) before barrier
#pragma unroll
        for (int kc = 0; kc < 2; ++kc) {
            f16x8 af[4], bf[4];
#pragma unroll
            for (int i = 0; i < 4; ++i)
                af[i] = *(const f16x8*)&As[wm * 64 + i * 16 + n15][(kc * 32 + g * 8) ^ sx];
#pragma unroll
            for (int i = 0; i < 4; ++i)
                bf[i] = *(const f16x8*)&Bs[wn * 64 + i * 16 + n15][(kc * 32 + g * 8) ^ sx];
#pragma unroll
            for (int mi = 0; mi < 4; ++mi)
#pragma unroll
                for (int ni = 0; ni < 4; ++ni)
                    acc[mi][ni] = MFMA_F16(af[mi], bf[ni], acc[mi][ni]);
        }
    }

    // epilogue — C/D frag: row = 4*g + r, col = n15
#pragma unroll
    for (int mi = 0; mi < 4; ++mi) {
        const int m0 = brow + wm * 64 + mi * 16 + g * 4;   // 4-aligned
        const int b  = m0 >> 11;
        const int s0 = m0 & (Sc - 1);
#pragma unroll
        for (int ni = 0; ni < 4; ++ni) {
            const int n = bcol + wn * 64 + ni * 16 + n15;
            if (mode == 1) {
                if (n >= HIDc) continue;
                float* dst = oF + (size_t)m0 * HIDc + n;
#pragma unroll
                for (int r = 0; r < 4; ++r)
                    dst[r * HIDc] = acc[mi][ni][r];
            } else {
                const int which = (n >= 2560) ? 2 : (n >= 1280 ? 1 : 0);
                const int nn = n - which * 1280;
                if (nn >= HIDc) continue;
                const int h = nn / 100, d = nn - h * 100;
                if (which == 0) {
                    f16* dst = outQ + ((size_t)(b * Hc + h) * Sc + s0) * DP + d;
#pragma unroll
                    for (int r = 0; r < 4; ++r)
                        dst[r * DP] = (f16)acc[mi][ni][r];
                } else if (which == 1) {
                    const size_t tb = ((size_t)(b * Hc + h) * NT + (s0 >> 6)) * TE;
#pragma unroll
                    for (int r = 0; r < 4; ++r) {
                        const int t = s0 + r;              // same tile for r=0..3
                        outK[tb + (t & 63) * DP + (d ^ ((t & 15) << 3))] = (f16)acc[mi][ni][r];
                    }
                } else {
                    const size_t tb = ((size_t)(b * Hc + h) * NT + (s0 >> 6)) * TE;
                    f16x4 pk;
#pragma unroll
                    for (int r = 0; r < 4; ++r) pk[r] = (f16)acc[mi][ni][r];
                    *(f16x4*)(outV + tb + d * 64 + ((s0 & 63) ^ ((d & 7) << 3))) = pk;
                }
            }
        }
    }
}

// ---------------- fused flash attention, 32x32 MFMA / in-register P ----------
// grid 768 1-D, XCD-swizzled. 4 waves/block, 32 q-rows each (q = lane&31).
// 2 barriers/tile: K double-buffered (2 tiles slack), V single (1 tile slack).
// Queue ledger at tile-t entry: {K(t) 4, V(t) 4, K(t+1) 4} -> vmcnt(4).
__launch_bounds__(256, 3)
__global__ void attn_kernel(const f16* __restrict__ Qp, const f16* __restrict__ KpT,
                            const f16* __restrict__ VpT, const int* __restrict__ lidx,
                            f16* __restrict__ outp) {
    __shared__ f16 Kl[2][64][128];     // 32 KB, double-buffered, 4-bit swizzle
    __shared__ f16 Vl[128][64];        // 16 KB, 3-bit swizzle

    const int tid  = threadIdx.x;
    const int lane = tid & 63, wave = tid >> 6;
    const int l31 = lane & 31, h = lane >> 5;
    const int sxk = (l31 & 15) << 3;   // K read XOR ((t&15) == (l31&15))
    const int sxv = (l31 & 7) << 3;    // V read XOR ((d&7) == (l31&7))

    const int bid = blockIdx.x;
    const int bh  = (bid & 7) * 6 + ((bid >> 3) >> 4);
    const int qt  = (bid >> 3) & 15;
    const int qr0 = qt * 128 + wave * 32;

    // log2-domain scale: exp(s*10/(L+1)) == exp2(s*10*log2e/(L+1))
    const float scale = 10.f * 1.44269504f / (float)(lidx[0] + 1);

    // Q rows in regs: 7 K-steps cover d=0..111 (d>=112 is structurally zero)
    const f16* Qb = Qp + ((size_t)bh * Sc + qr0 + l31) * DP + h * 8;
    f16x8 qreg[7];
#pragma unroll
    for (int st = 0; st < 7; ++st) {
        f16x8 v = *(const f16x8*)(Qb + st * 16);
#pragma unroll
        for (int e = 0; e < 8; ++e)
            v[e] = (f16)((float)v[e] * scale);
        qreg[st] = v;
    }

    float m_run = -1e30f, l_run = 0.f;
    f32x16 accO[4];                    // O^T block db: d = db*32+(reg&3)+8*(reg>>2)+4h, q=l31
#pragma unroll
    for (int db = 0; db < 4; ++db)
#pragma unroll
        for (int i = 0; i < 16; ++i)
            accO[db][i] = 0.f;

    const f16* Kbase = KpT + (size_t)bh * NT * TE;
    const f16* Vbase = VpT + (size_t)bh * NT * TE;

    // prologue: K0 -> Kl[0], V0 -> Vl, K1 -> Kl[1]
#pragma unroll
    for (int j = 0; j < 4; ++j) {
        const int c8 = (j * 256 + tid) * 8;
        gload16(Kbase + c8, &Kl[0][0][0] + c8);
    }
#pragma unroll
    for (int j = 0; j < 4; ++j) {
        const int c8 = (j * 256 + tid) * 8;
        gload16(Vbase + c8, &Vl[0][0] + c8);
    }
#pragma unroll
    for (int j = 0; j < 4; ++j) {
        const int c8 = (j * 256 + tid) * 8;
        gload16(Kbase + TE + c8, &Kl[1][0][0] + c8);
    }

    for (int tile = 0; tile < NT; ++tile) {
        const int kb = tile & 1;

        // barrier A: K(t)+V(t) complete (leave K(t+1)'s 4 in flight)
        if (tile == NT - 1) asm volatile("s_waitcnt vmcnt(0)" ::: "memory");
        else                asm volatile("s_waitcnt vmcnt(4)" ::: "memory");
        __builtin_amdgcn_s_barrier();
        __builtin_amdgcn_sched_barrier(0);

        // S^T = K Q^T: lane q=l31, t = tb*32+(reg&3)+8*(reg>>2)+4h
        f32x16 sc0, sc1;
#pragma unroll
        for (int i = 0; i < 16; ++i) { sc0[i] = 0.f; sc1[i] = 0.f; }
        __builtin_amdgcn_s_setprio(1);
#pragma unroll
        for (int st = 0; st < 7; ++st) {
            const int col = (st * 16 + h * 8) ^ sxk;
            f16x8 kf0 = *(const f16x8*)&Kl[kb][l31][col];
            f16x8 kf1 = *(const f16x8*)&Kl[kb][32 + l31][col];
            sc0 = MFMA32(kf0, qreg[st], sc0);
            sc1 = MFMA32(kf1, qreg[st], sc1);
        }
        __builtin_amdgcn_s_setprio(0);

        // softmax (lane-local + one shfl): tile max over 64 t for own q
        float tm = sc0[0];
#pragma unroll
        for (int i = 1; i < 16; ++i) tm = fmaxf(tm, sc0[i]);
#pragma unroll
        for (int i = 0; i < 16; ++i) tm = fmaxf(tm, sc1[i]);
        tm = fmaxf(tm, __shfl_xor(tm, 32));

        // defer-max (T13): rescale only when max grew by >8 (log2 domain)
        if (__any(tm > m_run + 8.f)) {
            const float mn = fmaxf(m_run, tm);
            const float al = exp2f(m_run - mn);
            m_run = mn;
            l_run *= al;
#pragma unroll
            for (int db = 0; db < 4; ++db) accO[db] *= al;
        }

        // P = exp2(s - m) in place; row-sum over all 64 t
        float ps = 0.f;
#pragma unroll
        for (int i = 0; i < 16; ++i) { sc0[i] = exp2f(sc0[i] - m_run); ps += sc0[i]; }
#pragma unroll
        for (int i = 0; i < 16; ++i) { sc1[i] = exp2f(sc1[i] - m_run); ps += sc1[i]; }
        ps += __shfl_xor(ps, 32);
        l_run += ps;

        // pack P -> PV B-frags: cvt_pkrtz + v_permlane32_swap_b32 (in-register)
        f16x8 pa[4];
        {
            int e0[4], e1[4];
#pragma unroll
            for (int c = 0; c < 4; ++c) {
                auto lo = __builtin_amdgcn_cvt_pkrtz(sc0[4 * c + 0], sc0[4 * c + 1]);
                auto hi = __builtin_amdgcn_cvt_pkrtz(sc0[4 * c + 2], sc0[4 * c + 3]);
                e0[c] = __builtin_bit_cast(int, lo);
                e1[c] = __builtin_bit_cast(int, hi);
            }
#pragma unroll
            for (int ks = 0; ks < 2; ++ks) {
                int a0 = e0[2 * ks], b0 = e0[2 * ks + 1];
                int a1 = e1[2 * ks], b1 = e1[2 * ks + 1];
                asm("v_permlane32_swap_b32 %0, %1" : "+v"(a0), "+v"(b0));
                asm("v_permlane32_swap_b32 %0, %1" : "+v"(a1), "+v"(b1));
                i32x4 w = {a0, a1, b0, b1};
                pa[ks] = __builtin_bit_cast(f16x8, w);
            }
#pragma unroll
            for (int c = 0; c < 4; ++c) {
                auto lo = __builtin_amdgcn_cvt_pkrtz(sc1[4 * c + 0], sc1[4 * c + 1]);
                auto hi = __builtin_amdgcn_cvt_pkrtz(sc1[4 * c + 2], sc1[4 * c + 3]);
                e0[c] = __builtin_bit_cast(int, lo);
                e1[c] = __builtin_bit_cast(int, hi);
            }
#pragma unroll
            for (int ks = 0; ks < 2; ++ks) {
                int a0 = e0[2 * ks], b0 = e0[2 * ks + 1];
                int a1 = e1[2 * ks], b1 = e1[2 * ks + 1];
                asm("v_permlane32_swap_b32 %0, %1" : "+v"(a0), "+v"(b0));
                asm("v_permlane32_swap_b32 %0, %1" : "+v"(a1), "+v"(b1));
                i32x4 w = {a0, a1, b0, b1};
                pa[2 + ks] = __builtin_bit_cast(f16x8, w);
            }
        }

        // O^T += V^T P^T: A = V^T[d][t] from Vl (ready since barrier A), B = pa
        __builtin_amdgcn_s_setprio(1);
#pragma unroll
        for (int kk = 0; kk < 4; ++kk) {
            const int col = (kk * 16 + h * 8) ^ sxv;
#pragma unroll
            for (int db = 0; db < 4; ++db) {
                f16x8 vf = *(const f16x8*)&Vl[db * 32 + l31][col];
                accO[db] = MFMA32(vf, pa[kk], accO[db]);
            }
        }
        __builtin_amdgcn_s_setprio(0);

        // barrier B: all waves done reading Kl[kb] and Vl -> safe to overwrite
        asm volatile("s_waitcnt lgkmcnt(0)" ::: "memory");
        __builtin_amdgcn_s_barrier();
        __builtin_amdgcn_sched_barrier(0);
        if (tile + 1 < NT) {
            const f16* Vn = Vbase + (size_t)(tile + 1) * TE;
#pragma unroll
            for (int j = 0; j < 4; ++j) {
                const int c8 = (j * 256 + tid) * 8;
                gload16(Vn + c8, &Vl[0][0] + c8);
            }
        }
        if (tile + 2 < NT) {
            const f16* Kn = Kbase + (size_t)(tile + 2) * TE;
            f16* Kd = &Kl[kb][0][0];
#pragma unroll
            for (int j = 0; j < 4; ++j) {
                const int c8 = (j * 256 + tid) * 8;
                gload16(Kn + c8, Kd + c8);
            }
        }
    }

    // epilogue: lane holds O[q=l31][d = db*32 + 8c + 4h + r] -> f16x4 stores
    const float rl = 1.f / l_run;
    f16* orow = outp + ((size_t)bh * Sc + qr0 + l31) * Dc;
#pragma unroll
    for (int db = 0; db < 4; ++db) {
#pragma unroll
        for (int c = 0; c < 4; ++c) {
            const int d0 = db * 32 + c * 8 + h * 4;
            if (d0 < Dc) {
                f16x4 o;
#pragma unroll
                for (int r = 0; r < 4; ++r)
                    o[r] = (f16)(accO[db][4 * c + r] * rl);
                *(f16x4*)(orow + d0) = o;
            }
        }
    }
}

// ---------------- launcher ----------------
extern "C" void kernel_launch(void* const* d_in, const int* in_sizes, int n_in,
                              void* d_out, int out_size, void* d_ws, size_t ws_size,
                              hipStream_t stream) {
    const float* x     = (const float*)d_in[0];
    const float* alibi = (const float*)d_in[1];
    const float* amask = (const float*)d_in[2];
    const float* wq    = (const float*)d_in[3];
    const float* wk    = (const float*)d_in[4];
    const float* wv    = (const float*)d_in[5];
    const float* wo    = (const float*)d_in[6];
    const int*   lidx  = (const int*)d_in[7];
    float* out = (float*)d_out;

    char* p = (char*)d_ws;
    auto carve = [&](size_t bytes) {
        char* q = p;
        p += (bytes + 255) & ~size_t(255);
        return q;
    };
    f16* x16  = (f16*)carve((size_t)(Bc * Sc) * LDK * 2);        // 8192 x 1216
    f16* wq16 = (f16*)carve((size_t)NWP * LDK * 2);              // 1280 x 1216 (wq/wk/wv contiguous!)
    f16* wk16 = (f16*)carve((size_t)NWP * LDK * 2);
    f16* wv16 = (f16*)carve((size_t)NWP * LDK * 2);
    f16* wo16 = (f16*)carve((size_t)NWP * LDK * 2);
    f16* QpL  = (f16*)carve((size_t)BH * Sc * DP * 2);           // (bh,s,128) linear
    f16* KpT  = (f16*)carve((size_t)BH * NT * TE * 2);           // swizzled tiles
    f16* VpT  = (f16*)carve((size_t)BH * NT * TE * 2);           // swizzled tiles
    f16* comb = (f16*)carve((size_t)BH * Sc * Dc * 2 + 4096);    // + overrun slack

    // 1) fp16 conversions (+ zero pads), x4-vectorized; weights merged 1 launch
    {
        int total4 = Bc * Sc * LDK / 4;
        cvt_pad4_kernel<<<(total4 + 255) / 256, 256, 0, stream>>>(x, x16, Bc * Sc, HIDc, LDK, total4);
    }
    {
        int total4 = NWP * LDK / 4;
        int nb = (total4 + 255) / 256;
        cvt_w_kernel<<<dim3(nb, 4), 256, 0, stream>>>(wq, wk, wv, wo,
                                                      wq16, wk16, wv16, wo16, total4);
    }
    // 2) pads of Q/K/V; K d=100 carries the alibi+mask bias (log2-domain trick)
    {
        int total = BH * Sc * (DP - Dc);
        pad_bufs_kernel<<<(total + 255) / 256, 256, 0, stream>>>(QpL, KpT, VpT, alibi, amask, lidx);
    }
    // 3) fused QKV projection: B = [wq16; wk16; wv16], N = 3840
    gemm_bt_kernel<<<dim3(64, 30), 256, 0, stream>>>(x16, LDK, wq16, QpL, KpT, VpT, nullptr, 0);
    // 4) fused attention (768 blocks, XCD-swizzled)
    attn_kernel<<<dim3(768), 256, 0, stream>>>(QpL, KpT, VpT, lidx, comb);
    // 5) output projection (reads comb linearly as 8192 x 1200; 16-elem row
    //    overrun lands on wo16's zero K-columns)
    gemm_bt_kernel<<<dim3(64, 10), 256, 0, stream>>>(comb, HIDc, wo16, nullptr, nullptr, nullptr, out, 1);
}